// Round 1
// baseline (366.331 us; speedup 1.0000x reference)
//
#include <hip/hip_runtime.h>

#define D 128
#define BN_EPS 1e-5f
#define NBUCK 256     // coarse buckets, dst>>9 (196 used at N=100K)
#define BSHIFT 9
#define NSLICE 8      // column slices of 16 cols; 1 slice = N*32B = 3.2MB -> fits 4MB XCD L2

using short8 = __attribute__((ext_vector_type(8))) short;
using floatx4 = __attribute__((ext_vector_type(4))) float;

__device__ inline unsigned short f2bf(float f) {
    unsigned u = __float_as_uint(f);
    u += 0x7fff + ((u >> 16) & 1);  // RNE
    return (unsigned short)(u >> 16);
}
__device__ inline float bf2f(unsigned short s) {
    return __uint_as_float(((unsigned)s) << 16);
}

// ---------- wt: Wt = bf16(W^T), BN affine; block 0 zeroes counters ----------
__global__ void wt_kernel(const float* __restrict__ W, const float* __restrict__ b,
                          const float* __restrict__ gamma, const float* __restrict__ beta,
                          const float* __restrict__ mean, const float* __restrict__ var,
                          unsigned short* __restrict__ Wt, float* __restrict__ scv,
                          float* __restrict__ pov, int* __restrict__ bucketTot,
                          int* __restrict__ resCnt) {
    int t = blockIdx.x * blockDim.x + threadIdx.x;
    int k = t >> 7, n = t & 127;
    Wt[(size_t)n * D + k] = f2bf(W[t]);
    if (t < D) {
        float sc = gamma[t] * rsqrtf(var[t] + BN_EPS);
        scv[t] = sc;
        pov[t] = (b[t] - mean[t]) * sc + beta[t];
    }
    if (blockIdx.x == 0 && threadIdx.x < NBUCK) {
        bucketTot[threadIdx.x] = 0;
        resCnt[threadIdx.x] = 0;
    }
}

// ---------- pA: global bucket histogram (LDS-aggregated) ----------
__global__ __launch_bounds__(256) void pA_kernel(const int* __restrict__ dst,
                                                 int* __restrict__ bucketTot, int E) {
    __shared__ int lh[NBUCK];
    int tid = threadIdx.x;
    lh[tid] = 0;
    __syncthreads();
    for (int i = blockIdx.x * 256 + tid; i < E; i += gridDim.x * 256)
        atomicAdd(&lh[dst[i] >> BSHIFT], 1);
    __syncthreads();
    if (lh[tid]) atomicAdd(&bucketTot[tid], lh[tid]);
}

// ---------- pB: partition into bucket order (self-scanned bases) ----------
__global__ __launch_bounds__(256) void pB_kernel(const int* __restrict__ src,
                                                 const int* __restrict__ dst,
                                                 const int* __restrict__ bucketTot,
                                                 int* __restrict__ resCnt,
                                                 int2* __restrict__ pairs, int E) {
    __shared__ int sb[NBUCK];
    __shared__ int lh[NBUCK];
    __shared__ int lcur[NBUCK];
    int tid = threadIdx.x;
    sb[tid] = bucketTot[tid];
    lh[tid] = 0;
    __syncthreads();
    for (int d = 1; d < NBUCK; d <<= 1) {
        int v = (tid >= d) ? sb[tid - d] : 0;
        __syncthreads();
        sb[tid] += v;
        __syncthreads();
    }
    // sb = inclusive scan; exclusive base for bucket t = sb[t] - bucketTot[t]
    int chunk = (E + gridDim.x - 1) / gridDim.x;
    int base = blockIdx.x * chunk;
    int lim = min(chunk, E - base);
    if (lim <= 0) return;
    for (int i = tid; i < lim; i += 256) atomicAdd(&lh[dst[base + i] >> BSHIFT], 1);
    __syncthreads();
    int c = lh[tid];
    lcur[tid] = c ? (sb[tid] - bucketTot[tid]) + atomicAdd(&resCnt[tid], c) : 0;
    __syncthreads();
    for (int i = tid; i < lim; i += 256) {
        int s = src[base + i], d2 = dst[base + i];
        int pos = atomicAdd(&lcur[d2 >> BSHIFT], 1);
        pairs[pos] = make_int2(s, d2);
    }
}

// ---------- sort: within-bucket counting sort -> deg, offs, colidx ----------
__global__ __launch_bounds__(512) void sort_kernel(const int2* __restrict__ pairs,
                                                   const int* __restrict__ bucketTot,
                                                   int* __restrict__ deg,
                                                   int* __restrict__ offs,
                                                   int* __restrict__ colidx, int N, int E) {
    __shared__ int sb[NBUCK];
    __shared__ int lh[512];
    __shared__ int lcur[512];
    int tid = threadIdx.x;
    int b = blockIdx.x;
    if (tid < NBUCK) sb[tid] = bucketTot[tid];
    __syncthreads();
    for (int d = 1; d < NBUCK; d <<= 1) {
        int v = 0;
        if (tid < NBUCK && tid >= d) v = sb[tid - d];
        __syncthreads();
        if (tid < NBUCK) sb[tid] += v;
        __syncthreads();
    }
    int cnt = bucketTot[b];
    int base = sb[b] - cnt;  // exclusive bucket base
    lh[tid] = 0;
    __syncthreads();
    for (int i = tid; i < cnt; i += 512)
        atomicAdd(&lh[pairs[base + i].y & 511], 1);
    __syncthreads();
    int orig = lh[tid];
    for (int d = 1; d < 512; d <<= 1) {
        int v = (tid >= d) ? lh[tid - d] : 0;
        __syncthreads();
        lh[tid] += v;
        __syncthreads();
    }
    int exc = lh[tid] - orig;
    int node = b * 512 + tid;
    if (node < N) {
        deg[node] = orig;
        offs[node] = base + exc;
    }
    lcur[tid] = exc;
    if (b == 0 && tid == 0) offs[N] = E;
    __syncthreads();
    for (int i = tid; i < cnt; i += 512) {
        int2 p = pairs[base + i];
        int pos = atomicAdd(&lcur[p.y & 511], 1);
        colidx[base + pos] = p.x;
    }
}

// ---------- xs build (SLICE-MAJOR bf16: [NSLICE][N][16]) + dinv, fused ----------
__global__ void xs_kernel(const float* __restrict__ x, const int* __restrict__ deg,
                          float* __restrict__ dinv, unsigned short* __restrict__ xs,
                          int total4, int N) {
    int i = blockIdx.x * blockDim.x + threadIdx.x;  // float4 index
    if (i >= total4) return;
    int node = i >> 5, q = i & 31;
    float dv = rsqrtf((float)(deg[node] + 1));
    if (q == 0) dinv[node] = dv;
    float4 f = ((const float4*)x)[i];
    ushort4 o;
    o.x = f2bf(dv * f.x); o.y = f2bf(dv * f.y);
    o.z = f2bf(dv * f.z); o.w = f2bf(dv * f.w);
    // cols q*4..q*4+3 -> slice q>>2, within-slice ushort4 chunk q&3
    ((ushort4*)xs)[((size_t)(q >> 2) * N + node) * 4 + (q & 3)] = o;
}

// ---------- fallback kernels (small-ws path) ----------
__global__ void deg_kernel(const int* __restrict__ dst, int* __restrict__ deg, int E) {
    int e = blockIdx.x * blockDim.x + threadIdx.x;
    if (e < E) atomicAdd(&deg[dst[e]], 1);
}

__global__ void dinv_kernel(const int* __restrict__ deg, float* __restrict__ dinv, int N) {
    int v = blockIdx.x * blockDim.x + threadIdx.x;
    if (v < N) dinv[v] = rsqrtf((float)(deg[v] + 1));
}

__global__ __launch_bounds__(256) void scan1_kernel(const int* __restrict__ deg,
                                                    int* __restrict__ bsum, int N) {
    __shared__ int s[256];
    int t = threadIdx.x;
    int v = blockIdx.x * 256 + t;
    s[t] = (v < N) ? deg[v] : 0;
    for (int st = 128; st > 0; st >>= 1) {
        __syncthreads();
        if (t < st) s[t] += s[t + st];
    }
    if (t == 0) bsum[blockIdx.x] = s[0];
}

__global__ __launch_bounds__(512) void scan2_kernel(int* __restrict__ bsum,
                                                    int* __restrict__ offs, int P, int N) {
    __shared__ int a[512];
    int t = threadIdx.x;
    int orig = (t < P) ? bsum[t] : 0;
    a[t] = orig;
    __syncthreads();
    for (int d = 1; d < 512; d <<= 1) {
        int tv = (t >= d) ? a[t - d] : 0;
        __syncthreads();
        a[t] += tv;
        __syncthreads();
    }
    if (t < P) bsum[t] = a[t] - orig;
    if (t == 0) offs[N] = a[511];
}

__global__ __launch_bounds__(256) void scan3_kernel(const int* __restrict__ deg,
                                                    const int* __restrict__ bsum,
                                                    int* __restrict__ offs,
                                                    int* __restrict__ cursor, int N) {
    __shared__ int a[256];
    int t = threadIdx.x;
    int v = blockIdx.x * 256 + t;
    int d = (v < N) ? deg[v] : 0;
    a[t] = d;
    __syncthreads();
    for (int st = 1; st < 256; st <<= 1) {
        int tv = (t >= st) ? a[t - st] : 0;
        __syncthreads();
        a[t] += tv;
        __syncthreads();
    }
    if (v < N) {
        int off = bsum[blockIdx.x] + a[t] - d;
        offs[v] = off;
        cursor[v] = off;
    }
}

__global__ void fill_kernel(const int* __restrict__ src, const int* __restrict__ dst,
                            int* __restrict__ cursor, int* __restrict__ colidx, int E) {
    int e = blockIdx.x * blockDim.x + threadIdx.x;
    if (e < E) {
        int d = dst[e];
        int pos = atomicAdd(&cursor[d], 1);
        colidx[pos] = src[e];
    }
}

// ---------- SLICED gather-aggregate: slice = blockIdx&7 -> one XCD owns one
// 3.2MB column slice (L2-resident). Wave = 8 groups x 8 lanes; group = 1 node,
// lane = 1 dword (2 cols) of the node's 32B slice-row. colidx/aggb are nt so
// streaming traffic doesn't evict the resident slice. ----------
__global__ __launch_bounds__(256, 8) void aggs_kernel(
    const unsigned short* __restrict__ xs, const float* __restrict__ dinv,
    const int* __restrict__ offs, const int* __restrict__ colidx,
    unsigned int* __restrict__ aggb, int N) {
    int slice = blockIdx.x & (NSLICE - 1);
    int chunk = blockIdx.x >> 3;
    int lane = threadIdx.x & 63;
    int wv = threadIdx.x >> 6;
    int g = lane >> 3, l = lane & 7;
    int node = chunk * 32 + wv * 8 + g;
    if (node >= N) return;  // no barriers below: divergent exit is safe

    const unsigned int* xsb = (const unsigned int*)xs + (size_t)slice * N * 8;
    float dv = dinv[node];
    unsigned int sv = xsb[(size_t)node * 8 + l];
    float a0 = bf2f((unsigned short)sv);
    float a1 = bf2f((unsigned short)(sv >> 16));
    int p = offs[node], pe = offs[node + 1];

    for (; p + 8 <= pe; p += 8) {
        int u[8];
        unsigned int v[8];
#pragma unroll
        for (int j = 0; j < 8; ++j) u[j] = __builtin_nontemporal_load(colidx + p + j);
#pragma unroll
        for (int j = 0; j < 8; ++j) v[j] = xsb[(size_t)u[j] * 8 + l];
#pragma unroll
        for (int j = 0; j < 8; ++j) {
            a0 += bf2f((unsigned short)v[j]);
            a1 += bf2f((unsigned short)(v[j] >> 16));
        }
    }
    for (; p + 4 <= pe; p += 4) {
        int u[4];
        unsigned int v[4];
#pragma unroll
        for (int j = 0; j < 4; ++j) u[j] = __builtin_nontemporal_load(colidx + p + j);
#pragma unroll
        for (int j = 0; j < 4; ++j) v[j] = xsb[(size_t)u[j] * 8 + l];
#pragma unroll
        for (int j = 0; j < 4; ++j) {
            a0 += bf2f((unsigned short)v[j]);
            a1 += bf2f((unsigned short)(v[j] >> 16));
        }
    }
    for (; p < pe; ++p) {
        unsigned int v = xsb[(size_t)__builtin_nontemporal_load(colidx + p) * 8 + l];
        a0 += bf2f((unsigned short)v);
        a1 += bf2f((unsigned short)(v >> 16));
    }
    unsigned int r =
        (unsigned int)f2bf(dv * a0) | ((unsigned int)f2bf(dv * a1) << 16);
    __builtin_nontemporal_store(r, aggb + (size_t)slice * N * 8 + (size_t)node * 8 + l);
}

// ---------- fallback aggregate (fp32, row-major, small-ws path) ----------
__global__ __launch_bounds__(256) void agg_kernel(
    const float* __restrict__ x, const float* __restrict__ dinv,
    const int* __restrict__ offs, const int* __restrict__ colidx,
    float* __restrict__ outp, int N) {
    int wid = (blockIdx.x * blockDim.x + threadIdx.x) >> 6;
    if (wid >= N) return;
    int lane = threadIdx.x & 63;
    float dv = dinv[wid];
    int p = offs[wid], pe = offs[wid + 1];
    const float2* x2 = (const float2*)x;
    float2 s = x2[(size_t)wid * 64 + lane];
    float a0 = dv * s.x;
    float a1 = dv * s.y;
    for (; p < pe; ++p) {
        int u = colidx[p];
        float du = dinv[u];
        float2 vv = x2[(size_t)u * 64 + lane];
        a0 += du * vv.x;
        a1 += du * vv.y;
    }
    float2 r;
    r.x = dv * a0;
    r.y = dv * a1;
    ((float2*)outp)[(size_t)wid * 64 + lane] = r;
}

// ---------- MFMA GEMM: out = relu(BN(agg @ W + b)) + x ----------
// aggb (if set) is SLICE-MAJOR [NSLICE][N][16] bf16.
__global__ __launch_bounds__(256) void gemm_kernel(
    float* __restrict__ outp, const float* __restrict__ xg,
    const unsigned short* __restrict__ Wt, const unsigned short* __restrict__ aggb,
    const float* __restrict__ scv, const float* __restrict__ pov, int nTiles, int N) {
    int wid = (blockIdx.x * blockDim.x + threadIdx.x) >> 6;
    if (wid >= nTiles) return;
    int lane = threadIdx.x & 63;
    int m = lane & 15, quad = lane >> 4;
    int row0 = wid * 16;

    short8 B[8][4];
#pragma unroll
    for (int cg = 0; cg < 8; ++cg)
#pragma unroll
        for (int ks = 0; ks < 4; ++ks)
            B[cg][ks] = *(const short8*)&Wt[(size_t)(cg * 16 + m) * D + ks * 32 + quad * 8];

    short8 A[4];
    if (aggb) {
        // col c -> slice c>>4, within-slice offset c&15. c0 = ks*32 + quad*8.
#pragma unroll
        for (int ks = 0; ks < 4; ++ks) {
            int sl = 2 * ks + (quad >> 1);
            A[ks] = *(const short8*)&aggb[((size_t)sl * N + row0 + m) * 16 + (quad & 1) * 8];
        }
    } else {
        const float* arow = outp + (size_t)(row0 + m) * D;
#pragma unroll
        for (int ks = 0; ks < 4; ++ks) {
            float4 f0 = *(const float4*)(arow + ks * 32 + quad * 8);
            float4 f1 = *(const float4*)(arow + ks * 32 + quad * 8 + 4);
            short8 af;
            af[0] = (short)f2bf(f0.x); af[1] = (short)f2bf(f0.y);
            af[2] = (short)f2bf(f0.z); af[3] = (short)f2bf(f0.w);
            af[4] = (short)f2bf(f1.x); af[5] = (short)f2bf(f1.y);
            af[6] = (short)f2bf(f1.z); af[7] = (short)f2bf(f1.w);
            A[ks] = af;
        }
    }

#pragma unroll
    for (int cg = 0; cg < 8; ++cg) {
        floatx4 acc = {0.f, 0.f, 0.f, 0.f};
#pragma unroll
        for (int ks = 0; ks < 4; ++ks)
            acc = __builtin_amdgcn_mfma_f32_16x16x32_bf16(A[ks], B[cg][ks], acc, 0, 0, 0);
        int col = cg * 16 + m;
        float sc = scv[col], po = pov[col];
#pragma unroll
        for (int i = 0; i < 4; ++i) {
            int row = row0 + quad * 4 + i;
            float bn = acc[i] * sc + po;
            size_t idx = (size_t)row * D + col;
            outp[idx] = fmaxf(bn, 0.f) + xg[idx];
        }
    }
}

extern "C" void kernel_launch(void* const* d_in, const int* in_sizes, int n_in,
                              void* d_out, int out_size, void* d_ws, size_t ws_size,
                              hipStream_t stream) {
    const float* x = (const float*)d_in[0];
    const int* edge = (const int*)d_in[1];
    const float* Wm = (const float*)d_in[2];
    const float* b = (const float*)d_in[3];
    const float* gamma = (const float*)d_in[4];
    const float* beta = (const float*)d_in[5];
    const float* mean = (const float*)d_in[6];
    const float* var = (const float*)d_in[7];
    float* out = (float*)d_out;

    int N = in_sizes[0] / D;
    int E = in_sizes[1] / 2;
    const int* src = edge;
    const int* dst = edge + E;
    int P = (N + 255) / 256;

    // ---- workspace layout ----
    char* w = (char*)d_ws;
    size_t cur = 0;
    auto take = [&](size_t bytes) -> void* {
        cur = (cur + 15) & ~(size_t)15;
        void* p = w + cur;
        cur += bytes;
        return p;
    };
    int* deg = (int*)take((size_t)N * 4);
    int* bucketTot = (int*)take(NBUCK * 4);
    int* resCnt = (int*)take(NBUCK * 4);
    float* dinv = (float*)take((size_t)N * 4);
    int* offs = (int*)take((size_t)(N + 1) * 4);
    int* cursor = (int*)take((size_t)N * 4);
    int* bsum = (int*)take((size_t)(P + 1) * 4);
    unsigned short* Wt = (unsigned short*)take((size_t)D * D * 2);
    float* scv = (float*)take(D * 4);
    float* pov = (float*)take(D * 4);
    int* colidx = (int*)take((size_t)E * 4);
    cur = (cur + 15) & ~(size_t)15;
    size_t fixedEnd = cur;

    size_t xsBytes = (size_t)N * D * 2;
    size_t zoneBytes = (xsBytes > (size_t)E * 8) ? xsBytes : (size_t)E * 8;
    bool fast = fixedEnd + xsBytes + zoneBytes <= ws_size;

    unsigned short* xs = nullptr;
    int2* pairs = nullptr;
    unsigned int* aggb = nullptr;
    if (fast) {
        xs = (unsigned short*)(w + fixedEnd);
        pairs = (int2*)(w + fixedEnd + xsBytes);        // dead after sort_kernel
        aggb = (unsigned int*)(w + fixedEnd + xsBytes); // aliases pairs
    }

    wt_kernel<<<(D * D) / 256, 256, 0, stream>>>(Wm, b, gamma, beta, mean, var, Wt, scv,
                                                 pov, bucketTot, resCnt);

    if (fast) {
        pA_kernel<<<1024, 256, 0, stream>>>(dst, bucketTot, E);
        pB_kernel<<<256, 256, 0, stream>>>(src, dst, bucketTot, resCnt, pairs, E);
        sort_kernel<<<NBUCK, 512, 0, stream>>>(pairs, bucketTot, deg, offs, colidx, N, E);
        xs_kernel<<<(N * 32 + 255) / 256, 256, 0, stream>>>(x, deg, dinv, xs, N * 32, N);
        int chunks = (N + 31) / 32;
        aggs_kernel<<<chunks * NSLICE, 256, 0, stream>>>(xs, dinv, offs, colidx, aggb, N);
    } else {
        hipMemsetAsync(deg, 0, sizeof(int) * N, stream);
        deg_kernel<<<(E + 255) / 256, 256, 0, stream>>>(dst, deg, E);
        dinv_kernel<<<(N + 255) / 256, 256, 0, stream>>>(deg, dinv, N);
        scan1_kernel<<<P, 256, 0, stream>>>(deg, bsum, N);
        scan2_kernel<<<1, 512, 0, stream>>>(bsum, offs, P, N);
        scan3_kernel<<<P, 256, 0, stream>>>(deg, bsum, offs, cursor, N);
        fill_kernel<<<(E + 255) / 256, 256, 0, stream>>>(src, dst, cursor, colidx, E);
        agg_kernel<<<(N * 64 + 255) / 256, 256, 0, stream>>>(x, dinv, offs, colidx, out, N);
    }
    int nTiles = (N + 15) / 16;
    gemm_kernel<<<(nTiles * 64 + 255) / 256, 256, 0, stream>>>(
        out, x, Wt, (const unsigned short*)aggb, scv, pov, nTiles, N);
}

// Round 2
// 310.060 us; speedup vs baseline: 1.1815x; 1.1815x over previous
//
#include <hip/hip_runtime.h>

#define D 128
#define BN_EPS 1e-5f
#define NBUCK 256     // coarse buckets, dst>>9 (196 used at N=100K)
#define BSHIFT 9
#define NSLICE 8      // column slices of 16 cols; 1 slice = N*32B = 3.2MB -> fits 4MB XCD L2

using short8 = __attribute__((ext_vector_type(8))) short;
using floatx4 = __attribute__((ext_vector_type(4))) float;

__device__ inline unsigned short f2bf(float f) {
    unsigned u = __float_as_uint(f);
    u += 0x7fff + ((u >> 16) & 1);  // RNE
    return (unsigned short)(u >> 16);
}
__device__ inline float bf2f(unsigned short s) {
    return __uint_as_float(((unsigned)s) << 16);
}

// ---------- wt: Wt = bf16(W^T), BN affine; block 0 zeroes counters ----------
__global__ void wt_kernel(const float* __restrict__ W, const float* __restrict__ b,
                          const float* __restrict__ gamma, const float* __restrict__ beta,
                          const float* __restrict__ mean, const float* __restrict__ var,
                          unsigned short* __restrict__ Wt, float* __restrict__ scv,
                          float* __restrict__ pov, int* __restrict__ bucketTot,
                          int* __restrict__ resCnt) {
    int t = blockIdx.x * blockDim.x + threadIdx.x;
    int k = t >> 7, n = t & 127;
    Wt[(size_t)n * D + k] = f2bf(W[t]);
    if (t < D) {
        float sc = gamma[t] * rsqrtf(var[t] + BN_EPS);
        scv[t] = sc;
        pov[t] = (b[t] - mean[t]) * sc + beta[t];
    }
    if (blockIdx.x == 0 && threadIdx.x < NBUCK) {
        bucketTot[threadIdx.x] = 0;
        resCnt[threadIdx.x] = 0;
    }
}

// ---------- pA: global bucket histogram (LDS-aggregated) ----------
__global__ __launch_bounds__(256) void pA_kernel(const int* __restrict__ dst,
                                                 int* __restrict__ bucketTot, int E) {
    __shared__ int lh[NBUCK];
    int tid = threadIdx.x;
    lh[tid] = 0;
    __syncthreads();
    for (int i = blockIdx.x * 256 + tid; i < E; i += gridDim.x * 256)
        atomicAdd(&lh[dst[i] >> BSHIFT], 1);
    __syncthreads();
    if (lh[tid]) atomicAdd(&bucketTot[tid], lh[tid]);
}

// ---------- pB: partition into bucket order (self-scanned bases) ----------
__global__ __launch_bounds__(256) void pB_kernel(const int* __restrict__ src,
                                                 const int* __restrict__ dst,
                                                 const int* __restrict__ bucketTot,
                                                 int* __restrict__ resCnt,
                                                 int2* __restrict__ pairs, int E) {
    __shared__ int sb[NBUCK];
    __shared__ int lh[NBUCK];
    __shared__ int lcur[NBUCK];
    int tid = threadIdx.x;
    sb[tid] = bucketTot[tid];
    lh[tid] = 0;
    __syncthreads();
    for (int d = 1; d < NBUCK; d <<= 1) {
        int v = (tid >= d) ? sb[tid - d] : 0;
        __syncthreads();
        sb[tid] += v;
        __syncthreads();
    }
    // sb = inclusive scan; exclusive base for bucket t = sb[t] - bucketTot[t]
    int chunk = (E + gridDim.x - 1) / gridDim.x;
    int base = blockIdx.x * chunk;
    int lim = min(chunk, E - base);
    if (lim <= 0) return;
    for (int i = tid; i < lim; i += 256) atomicAdd(&lh[dst[base + i] >> BSHIFT], 1);
    __syncthreads();
    int c = lh[tid];
    lcur[tid] = c ? (sb[tid] - bucketTot[tid]) + atomicAdd(&resCnt[tid], c) : 0;
    __syncthreads();
    for (int i = tid; i < lim; i += 256) {
        int s = src[base + i], d2 = dst[base + i];
        int pos = atomicAdd(&lcur[d2 >> BSHIFT], 1);
        pairs[pos] = make_int2(s, d2);
    }
}

// ---------- sort: within-bucket counting sort -> deg, offs, colidx ----------
__global__ __launch_bounds__(512) void sort_kernel(const int2* __restrict__ pairs,
                                                   const int* __restrict__ bucketTot,
                                                   int* __restrict__ deg,
                                                   int* __restrict__ offs,
                                                   int* __restrict__ colidx, int N, int E) {
    __shared__ int sb[NBUCK];
    __shared__ int lh[512];
    __shared__ int lcur[512];
    int tid = threadIdx.x;
    int b = blockIdx.x;
    if (tid < NBUCK) sb[tid] = bucketTot[tid];
    __syncthreads();
    for (int d = 1; d < NBUCK; d <<= 1) {
        int v = 0;
        if (tid < NBUCK && tid >= d) v = sb[tid - d];
        __syncthreads();
        if (tid < NBUCK) sb[tid] += v;
        __syncthreads();
    }
    int cnt = bucketTot[b];
    int base = sb[b] - cnt;  // exclusive bucket base
    lh[tid] = 0;
    __syncthreads();
    for (int i = tid; i < cnt; i += 512)
        atomicAdd(&lh[pairs[base + i].y & 511], 1);
    __syncthreads();
    int orig = lh[tid];
    for (int d = 1; d < 512; d <<= 1) {
        int v = (tid >= d) ? lh[tid - d] : 0;
        __syncthreads();
        lh[tid] += v;
        __syncthreads();
    }
    int exc = lh[tid] - orig;
    int node = b * 512 + tid;
    if (node < N) {
        deg[node] = orig;
        offs[node] = base + exc;
    }
    lcur[tid] = exc;
    if (b == 0 && tid == 0) offs[N] = E;
    __syncthreads();
    for (int i = tid; i < cnt; i += 512) {
        int2 p = pairs[base + i];
        int pos = atomicAdd(&lcur[p.y & 511], 1);
        colidx[base + pos] = p.x;
    }
}

// ---------- xs build (SLICE-MAJOR bf16: [NSLICE][N][16]) + dinv, fused ----------
__global__ void xs_kernel(const float* __restrict__ x, const int* __restrict__ deg,
                          float* __restrict__ dinv, unsigned short* __restrict__ xs,
                          int total4, int N) {
    int i = blockIdx.x * blockDim.x + threadIdx.x;  // float4 index
    if (i >= total4) return;
    int node = i >> 5, q = i & 31;
    float dv = rsqrtf((float)(deg[node] + 1));
    if (q == 0) dinv[node] = dv;
    float4 f = ((const float4*)x)[i];
    ushort4 o;
    o.x = f2bf(dv * f.x); o.y = f2bf(dv * f.y);
    o.z = f2bf(dv * f.z); o.w = f2bf(dv * f.w);
    // cols q*4..q*4+3 -> slice q>>2, within-slice ushort4 chunk q&3
    ((ushort4*)xs)[((size_t)(q >> 2) * N + node) * 4 + (q & 3)] = o;
}

// ---------- fallback kernels (small-ws path) ----------
__global__ void deg_kernel(const int* __restrict__ dst, int* __restrict__ deg, int E) {
    int e = blockIdx.x * blockDim.x + threadIdx.x;
    if (e < E) atomicAdd(&deg[dst[e]], 1);
}

__global__ void dinv_kernel(const int* __restrict__ deg, float* __restrict__ dinv, int N) {
    int v = blockIdx.x * blockDim.x + threadIdx.x;
    if (v < N) dinv[v] = rsqrtf((float)(deg[v] + 1));
}

__global__ __launch_bounds__(256) void scan1_kernel(const int* __restrict__ deg,
                                                    int* __restrict__ bsum, int N) {
    __shared__ int s[256];
    int t = threadIdx.x;
    int v = blockIdx.x * 256 + t;
    s[t] = (v < N) ? deg[v] : 0;
    for (int st = 128; st > 0; st >>= 1) {
        __syncthreads();
        if (t < st) s[t] += s[t + st];
    }
    if (t == 0) bsum[blockIdx.x] = s[0];
}

__global__ __launch_bounds__(512) void scan2_kernel(int* __restrict__ bsum,
                                                    int* __restrict__ offs, int P, int N) {
    __shared__ int a[512];
    int t = threadIdx.x;
    int orig = (t < P) ? bsum[t] : 0;
    a[t] = orig;
    __syncthreads();
    for (int d = 1; d < 512; d <<= 1) {
        int tv = (t >= d) ? a[t - d] : 0;
        __syncthreads();
        a[t] += tv;
        __syncthreads();
    }
    if (t < P) bsum[t] = a[t] - orig;
    if (t == 0) offs[N] = a[511];
}

__global__ __launch_bounds__(256) void scan3_kernel(const int* __restrict__ deg,
                                                    const int* __restrict__ bsum,
                                                    int* __restrict__ offs,
                                                    int* __restrict__ cursor, int N) {
    __shared__ int a[256];
    int t = threadIdx.x;
    int v = blockIdx.x * 256 + t;
    int d = (v < N) ? deg[v] : 0;
    a[t] = d;
    __syncthreads();
    for (int st = 1; st < 256; st <<= 1) {
        int tv = (t >= st) ? a[t - st] : 0;
        __syncthreads();
        a[t] += tv;
        __syncthreads();
    }
    if (v < N) {
        int off = bsum[blockIdx.x] + a[t] - d;
        offs[v] = off;
        cursor[v] = off;
    }
}

__global__ void fill_kernel(const int* __restrict__ src, const int* __restrict__ dst,
                            int* __restrict__ cursor, int* __restrict__ colidx, int E) {
    int e = blockIdx.x * blockDim.x + threadIdx.x;
    if (e < E) {
        int d = dst[e];
        int pos = atomicAdd(&cursor[d], 1);
        colidx[pos] = src[e];
    }
}

// ---------- SLICED gather-aggregate: slice = blockIdx&7 -> one XCD owns one
// 3.2MB column slice (L2-resident). Wave = 8 groups x 8 lanes; group = 1 node,
// lane = 1 dword (2 cols) of the node's 32B slice-row.
// colidx loads are CACHED (L3-resident across slice passes, ~300cy not ~900cy
// on the chain head). Depth-16 batches + a single predicated tail batch keep
// 16+ gathers outstanding per thread; no serial scalar tail. ----------
__global__ __launch_bounds__(256, 8) void aggs_kernel(
    const unsigned short* __restrict__ xs, const float* __restrict__ dinv,
    const int* __restrict__ offs, const int* __restrict__ colidx,
    unsigned int* __restrict__ aggb, int N) {
    int slice = blockIdx.x & (NSLICE - 1);
    int chunk = blockIdx.x >> 3;
    int lane = threadIdx.x & 63;
    int wv = threadIdx.x >> 6;
    int g = lane >> 3, l = lane & 7;
    int node = chunk * 32 + wv * 8 + g;
    if (node >= N) return;  // no barriers below: divergent exit is safe

    const unsigned int* xsb = (const unsigned int*)xs + (size_t)slice * N * 8;
    float dv = dinv[node];
    unsigned int sv = xsb[(size_t)node * 8 + l];
    float a0 = bf2f((unsigned short)sv);
    float a1 = bf2f((unsigned short)(sv >> 16));
    int p = offs[node], pe = offs[node + 1];

    for (; p + 16 <= pe; p += 16) {
        int u[16];
        unsigned int v[16];
#pragma unroll
        for (int j = 0; j < 16; ++j) u[j] = colidx[p + j];
#pragma unroll
        for (int j = 0; j < 16; ++j) v[j] = xsb[(size_t)u[j] * 8 + l];
#pragma unroll
        for (int j = 0; j < 16; ++j) {
            a0 += bf2f((unsigned short)v[j]);
            a1 += bf2f((unsigned short)(v[j] >> 16));
        }
    }
    int rem = pe - p;  // 0..15, uniform within the 8-lane group
    if (rem > 0) {
        int u[16];
        unsigned int v[16];
#pragma unroll
        for (int j = 0; j < 16; ++j) u[j] = (j < rem) ? colidx[p + j] : 0;
#pragma unroll
        for (int j = 0; j < 16; ++j)
            v[j] = (j < rem) ? xsb[(size_t)u[j] * 8 + l] : 0u;
#pragma unroll
        for (int j = 0; j < 16; ++j) {
            a0 += bf2f((unsigned short)v[j]);
            a1 += bf2f((unsigned short)(v[j] >> 16));
        }
    }
    unsigned int r =
        (unsigned int)f2bf(dv * a0) | ((unsigned int)f2bf(dv * a1) << 16);
    __builtin_nontemporal_store(r, aggb + (size_t)slice * N * 8 + (size_t)node * 8 + l);
}

// ---------- fallback aggregate (fp32, row-major, small-ws path) ----------
__global__ __launch_bounds__(256) void agg_kernel(
    const float* __restrict__ x, const float* __restrict__ dinv,
    const int* __restrict__ offs, const int* __restrict__ colidx,
    float* __restrict__ outp, int N) {
    int wid = (blockIdx.x * blockDim.x + threadIdx.x) >> 6;
    if (wid >= N) return;
    int lane = threadIdx.x & 63;
    float dv = dinv[wid];
    int p = offs[wid], pe = offs[wid + 1];
    const float2* x2 = (const float2*)x;
    float2 s = x2[(size_t)wid * 64 + lane];
    float a0 = dv * s.x;
    float a1 = dv * s.y;
    for (; p < pe; ++p) {
        int u = colidx[p];
        float du = dinv[u];
        float2 vv = x2[(size_t)u * 64 + lane];
        a0 += du * vv.x;
        a1 += du * vv.y;
    }
    float2 r;
    r.x = dv * a0;
    r.y = dv * a1;
    ((float2*)outp)[(size_t)wid * 64 + lane] = r;
}

// ---------- MFMA GEMM: out = relu(BN(agg @ W + b)) + x ----------
// aggb (if set) is SLICE-MAJOR [NSLICE][N][16] bf16.
__global__ __launch_bounds__(256) void gemm_kernel(
    float* __restrict__ outp, const float* __restrict__ xg,
    const unsigned short* __restrict__ Wt, const unsigned short* __restrict__ aggb,
    const float* __restrict__ scv, const float* __restrict__ pov, int nTiles, int N) {
    int wid = (blockIdx.x * blockDim.x + threadIdx.x) >> 6;
    if (wid >= nTiles) return;
    int lane = threadIdx.x & 63;
    int m = lane & 15, quad = lane >> 4;
    int row0 = wid * 16;

    short8 B[8][4];
#pragma unroll
    for (int cg = 0; cg < 8; ++cg)
#pragma unroll
        for (int ks = 0; ks < 4; ++ks)
            B[cg][ks] = *(const short8*)&Wt[(size_t)(cg * 16 + m) * D + ks * 32 + quad * 8];

    short8 A[4];
    if (aggb) {
        // col c -> slice c>>4, within-slice offset c&15. c0 = ks*32 + quad*8.
#pragma unroll
        for (int ks = 0; ks < 4; ++ks) {
            int sl = 2 * ks + (quad >> 1);
            A[ks] = *(const short8*)&aggb[((size_t)sl * N + row0 + m) * 16 + (quad & 1) * 8];
        }
    } else {
        const float* arow = outp + (size_t)(row0 + m) * D;
#pragma unroll
        for (int ks = 0; ks < 4; ++ks) {
            float4 f0 = *(const float4*)(arow + ks * 32 + quad * 8);
            float4 f1 = *(const float4*)(arow + ks * 32 + quad * 8 + 4);
            short8 af;
            af[0] = (short)f2bf(f0.x); af[1] = (short)f2bf(f0.y);
            af[2] = (short)f2bf(f0.z); af[3] = (short)f2bf(f0.w);
            af[4] = (short)f2bf(f1.x); af[5] = (short)f2bf(f1.y);
            af[6] = (short)f2bf(f1.z); af[7] = (short)f2bf(f1.w);
            A[ks] = af;
        }
    }

#pragma unroll
    for (int cg = 0; cg < 8; ++cg) {
        floatx4 acc = {0.f, 0.f, 0.f, 0.f};
#pragma unroll
        for (int ks = 0; ks < 4; ++ks)
            acc = __builtin_amdgcn_mfma_f32_16x16x32_bf16(A[ks], B[cg][ks], acc, 0, 0, 0);
        int col = cg * 16 + m;
        float sc = scv[col], po = pov[col];
#pragma unroll
        for (int i = 0; i < 4; ++i) {
            int row = row0 + quad * 4 + i;
            float bn = acc[i] * sc + po;
            size_t idx = (size_t)row * D + col;
            outp[idx] = fmaxf(bn, 0.f) + xg[idx];
        }
    }
}

extern "C" void kernel_launch(void* const* d_in, const int* in_sizes, int n_in,
                              void* d_out, int out_size, void* d_ws, size_t ws_size,
                              hipStream_t stream) {
    const float* x = (const float*)d_in[0];
    const int* edge = (const int*)d_in[1];
    const float* Wm = (const float*)d_in[2];
    const float* b = (const float*)d_in[3];
    const float* gamma = (const float*)d_in[4];
    const float* beta = (const float*)d_in[5];
    const float* mean = (const float*)d_in[6];
    const float* var = (const float*)d_in[7];
    float* out = (float*)d_out;

    int N = in_sizes[0] / D;
    int E = in_sizes[1] / 2;
    const int* src = edge;
    const int* dst = edge + E;
    int P = (N + 255) / 256;

    // ---- workspace layout ----
    char* w = (char*)d_ws;
    size_t cur = 0;
    auto take = [&](size_t bytes) -> void* {
        cur = (cur + 15) & ~(size_t)15;
        void* p = w + cur;
        cur += bytes;
        return p;
    };
    int* deg = (int*)take((size_t)N * 4);
    int* bucketTot = (int*)take(NBUCK * 4);
    int* resCnt = (int*)take(NBUCK * 4);
    float* dinv = (float*)take((size_t)N * 4);
    int* offs = (int*)take((size_t)(N + 1) * 4);
    int* cursor = (int*)take((size_t)N * 4);
    int* bsum = (int*)take((size_t)(P + 1) * 4);
    unsigned short* Wt = (unsigned short*)take((size_t)D * D * 2);
    float* scv = (float*)take(D * 4);
    float* pov = (float*)take(D * 4);
    int* colidx = (int*)take((size_t)E * 4);
    cur = (cur + 15) & ~(size_t)15;
    size_t fixedEnd = cur;

    size_t xsBytes = (size_t)N * D * 2;
    size_t zoneBytes = (xsBytes > (size_t)E * 8) ? xsBytes : (size_t)E * 8;
    bool fast = fixedEnd + xsBytes + zoneBytes <= ws_size;

    unsigned short* xs = nullptr;
    int2* pairs = nullptr;
    unsigned int* aggb = nullptr;
    if (fast) {
        xs = (unsigned short*)(w + fixedEnd);
        pairs = (int2*)(w + fixedEnd + xsBytes);        // dead after sort_kernel
        aggb = (unsigned int*)(w + fixedEnd + xsBytes); // aliases pairs
    }

    wt_kernel<<<(D * D) / 256, 256, 0, stream>>>(Wm, b, gamma, beta, mean, var, Wt, scv,
                                                 pov, bucketTot, resCnt);

    if (fast) {
        pA_kernel<<<1024, 256, 0, stream>>>(dst, bucketTot, E);
        pB_kernel<<<256, 256, 0, stream>>>(src, dst, bucketTot, resCnt, pairs, E);
        sort_kernel<<<NBUCK, 512, 0, stream>>>(pairs, bucketTot, deg, offs, colidx, N, E);
        xs_kernel<<<(N * 32 + 255) / 256, 256, 0, stream>>>(x, deg, dinv, xs, N * 32, N);
        int chunks = (N + 31) / 32;
        aggs_kernel<<<chunks * NSLICE, 256, 0, stream>>>(xs, dinv, offs, colidx, aggb, N);
    } else {
        hipMemsetAsync(deg, 0, sizeof(int) * N, stream);
        deg_kernel<<<(E + 255) / 256, 256, 0, stream>>>(dst, deg, E);
        dinv_kernel<<<(N + 255) / 256, 256, 0, stream>>>(deg, dinv, N);
        scan1_kernel<<<P, 256, 0, stream>>>(deg, bsum, N);
        scan2_kernel<<<1, 512, 0, stream>>>(bsum, offs, P, N);
        scan3_kernel<<<P, 256, 0, stream>>>(deg, bsum, offs, cursor, N);
        fill_kernel<<<(E + 255) / 256, 256, 0, stream>>>(src, dst, cursor, colidx, E);
        agg_kernel<<<(N * 64 + 255) / 256, 256, 0, stream>>>(x, dinv, offs, colidx, out, N);
    }
    int nTiles = (N + 15) / 16;
    gemm_kernel<<<(nTiles * 64 + 255) / 256, 256, 0, stream>>>(
        out, x, Wt, (const unsigned short*)aggb, scv, pov, nTiles, N);
}

// Round 3
// 301.698 us; speedup vs baseline: 1.2142x; 1.0277x over previous
//
#include <hip/hip_runtime.h>

#define D 128
#define BN_EPS 1e-5f
#define NBUCK 512     // coarse buckets, dst>>8 (391 used at N=100K), 256 nodes/bucket
#define BSHIFT 8
#define BNODES 256    // nodes per bucket

using short8 = __attribute__((ext_vector_type(8))) short;
using floatx4 = __attribute__((ext_vector_type(4))) float;

__device__ inline unsigned short f2bf(float f) {
    unsigned u = __float_as_uint(f);
    u += 0x7fff + ((u >> 16) & 1);  // RNE
    return (unsigned short)(u >> 16);
}
__device__ inline float bf2f(unsigned short s) {
    return __uint_as_float(((unsigned)s) << 16);
}

// ---------- wt: Wt = bf16(W^T), BN affine; first blocks zero counters ----------
__global__ void wt_kernel(const float* __restrict__ W, const float* __restrict__ b,
                          const float* __restrict__ gamma, const float* __restrict__ beta,
                          const float* __restrict__ mean, const float* __restrict__ var,
                          unsigned short* __restrict__ Wt, float* __restrict__ scv,
                          float* __restrict__ pov, int* __restrict__ bucketTot,
                          int* __restrict__ resCnt) {
    int t = blockIdx.x * blockDim.x + threadIdx.x;
    int k = t >> 7, n = t & 127;
    Wt[(size_t)n * D + k] = f2bf(W[t]);
    if (t < D) {
        float sc = gamma[t] * rsqrtf(var[t] + BN_EPS);
        scv[t] = sc;
        pov[t] = (b[t] - mean[t]) * sc + beta[t];
    }
    if (t < NBUCK) {
        bucketTot[t] = 0;
        resCnt[t] = 0;
    }
}

// ---------- pA: global bucket histogram (LDS-aggregated) ----------
__global__ __launch_bounds__(512) void pA_kernel(const int* __restrict__ dst,
                                                 int* __restrict__ bucketTot, int E) {
    __shared__ int lh[NBUCK];
    int tid = threadIdx.x;
    lh[tid] = 0;
    __syncthreads();
    for (int i = blockIdx.x * 512 + tid; i < E; i += gridDim.x * 512)
        atomicAdd(&lh[dst[i] >> BSHIFT], 1);
    __syncthreads();
    if (lh[tid]) atomicAdd(&bucketTot[tid], lh[tid]);
}

// ---------- pB: partition into bucket order (self-scanned bases) ----------
__global__ __launch_bounds__(512) void pB_kernel(const int* __restrict__ src,
                                                 const int* __restrict__ dst,
                                                 const int* __restrict__ bucketTot,
                                                 int* __restrict__ resCnt,
                                                 int2* __restrict__ pairs, int E) {
    __shared__ int sb[NBUCK];
    __shared__ int lh[NBUCK];
    __shared__ int lcur[NBUCK];
    int tid = threadIdx.x;
    sb[tid] = bucketTot[tid];
    lh[tid] = 0;
    __syncthreads();
    for (int d = 1; d < NBUCK; d <<= 1) {
        int v = (tid >= d) ? sb[tid - d] : 0;
        __syncthreads();
        sb[tid] += v;
        __syncthreads();
    }
    // sb = inclusive scan; exclusive base for bucket t = sb[t] - bucketTot[t]
    int chunk = (E + gridDim.x - 1) / gridDim.x;
    int base = blockIdx.x * chunk;
    int lim = min(chunk, E - base);
    if (lim <= 0) return;
    for (int i = tid; i < lim; i += 512) atomicAdd(&lh[dst[base + i] >> BSHIFT], 1);
    __syncthreads();
    int c = lh[tid];
    lcur[tid] = c ? (sb[tid] - bucketTot[tid]) + atomicAdd(&resCnt[tid], c) : 0;
    __syncthreads();
    for (int i = tid; i < lim; i += 512) {
        int s = src[base + i], d2 = dst[base + i];
        int pos = atomicAdd(&lcur[d2 >> BSHIFT], 1);
        pairs[pos] = make_int2(s, d2);
    }
}

// ---------- sort: within-bucket counting sort -> deg, offs, colidx ----------
// One block per bucket (BNODES=256 nodes). Produces deg/offs coalesced and
// colidx grouped by dst; all writes in the bucket's own ~12.5KB window.
__global__ __launch_bounds__(512) void sort_kernel(const int2* __restrict__ pairs,
                                                   const int* __restrict__ bucketTot,
                                                   int* __restrict__ deg,
                                                   int* __restrict__ offs,
                                                   int* __restrict__ colidx, int N, int E) {
    __shared__ int sb[NBUCK];
    __shared__ int lh[BNODES];
    __shared__ int lcur[BNODES];
    int tid = threadIdx.x;
    int b = blockIdx.x;
    sb[tid] = bucketTot[tid];
    __syncthreads();
    for (int d = 1; d < NBUCK; d <<= 1) {
        int v = (tid >= d) ? sb[tid - d] : 0;
        __syncthreads();
        sb[tid] += v;
        __syncthreads();
    }
    int cnt = bucketTot[b];
    int base = sb[b] - cnt;  // exclusive bucket base
    if (tid < BNODES) lh[tid] = 0;
    __syncthreads();
    for (int i = tid; i < cnt; i += 512)
        atomicAdd(&lh[pairs[base + i].y & (BNODES - 1)], 1);
    __syncthreads();
    int orig = (tid < BNODES) ? lh[tid] : 0;
    for (int d = 1; d < BNODES; d <<= 1) {
        int v = (tid < BNODES && tid >= d) ? lh[tid - d] : 0;
        __syncthreads();
        if (tid < BNODES) lh[tid] += v;
        __syncthreads();
    }
    if (tid < BNODES) {
        int exc = lh[tid] - orig;
        int node = b * BNODES + tid;
        if (node < N) {
            deg[node] = orig;
            offs[node] = base + exc;
        }
        lcur[tid] = exc;
    }
    if (b == 0 && tid == 0) offs[N] = E;
    __syncthreads();
    for (int i = tid; i < cnt; i += 512) {
        int2 p = pairs[base + i];
        int pos = atomicAdd(&lcur[p.y & (BNODES - 1)], 1);
        colidx[base + pos] = p.x;
    }
}

// ---------- xs build (row-major bf16) + dinv, fused ----------
__global__ void xs_kernel(const float* __restrict__ x, const int* __restrict__ deg,
                          float* __restrict__ dinv, unsigned short* __restrict__ xs,
                          int total4) {
    int i = blockIdx.x * blockDim.x + threadIdx.x;  // float4 index
    if (i >= total4) return;
    int node = i >> 5, q = i & 31;
    float dv = rsqrtf((float)(deg[node] + 1));
    if (q == 0) dinv[node] = dv;
    float4 f = ((const float4*)x)[i];
    ushort4 o;
    o.x = f2bf(dv * f.x); o.y = f2bf(dv * f.y);
    o.z = f2bf(dv * f.z); o.w = f2bf(dv * f.w);
    ((ushort4*)xs)[i] = o;
}

// ---------- fallback kernels (small-ws path) ----------
__global__ void deg_kernel(const int* __restrict__ dst, int* __restrict__ deg, int E) {
    int e = blockIdx.x * blockDim.x + threadIdx.x;
    if (e < E) atomicAdd(&deg[dst[e]], 1);
}

__global__ void dinv_kernel(const int* __restrict__ deg, float* __restrict__ dinv, int N) {
    int v = blockIdx.x * blockDim.x + threadIdx.x;
    if (v < N) dinv[v] = rsqrtf((float)(deg[v] + 1));
}

__global__ __launch_bounds__(256) void scan1_kernel(const int* __restrict__ deg,
                                                    int* __restrict__ bsum, int N) {
    __shared__ int s[256];
    int t = threadIdx.x;
    int v = blockIdx.x * 256 + t;
    s[t] = (v < N) ? deg[v] : 0;
    for (int st = 128; st > 0; st >>= 1) {
        __syncthreads();
        if (t < st) s[t] += s[t + st];
    }
    if (t == 0) bsum[blockIdx.x] = s[0];
}

__global__ __launch_bounds__(512) void scan2_kernel(int* __restrict__ bsum,
                                                    int* __restrict__ offs, int P, int N) {
    __shared__ int a[512];
    int t = threadIdx.x;
    int orig = (t < P) ? bsum[t] : 0;
    a[t] = orig;
    __syncthreads();
    for (int d = 1; d < 512; d <<= 1) {
        int tv = (t >= d) ? a[t - d] : 0;
        __syncthreads();
        a[t] += tv;
        __syncthreads();
    }
    if (t < P) bsum[t] = a[t] - orig;
    if (t == 0) offs[N] = a[511];
}

__global__ __launch_bounds__(256) void scan3_kernel(const int* __restrict__ deg,
                                                    const int* __restrict__ bsum,
                                                    int* __restrict__ offs,
                                                    int* __restrict__ cursor, int N) {
    __shared__ int a[256];
    int t = threadIdx.x;
    int v = blockIdx.x * 256 + t;
    int d = (v < N) ? deg[v] : 0;
    a[t] = d;
    __syncthreads();
    for (int st = 1; st < 256; st <<= 1) {
        int tv = (t >= st) ? a[t - st] : 0;
        __syncthreads();
        a[t] += tv;
        __syncthreads();
    }
    if (v < N) {
        int off = bsum[blockIdx.x] + a[t] - d;
        offs[v] = off;
        cursor[v] = off;
    }
}

__global__ void fill_kernel(const int* __restrict__ src, const int* __restrict__ dst,
                            int* __restrict__ cursor, int* __restrict__ colidx, int E) {
    int e = blockIdx.x * blockDim.x + threadIdx.x;
    if (e < E) {
        int d = dst[e];
        int pos = atomicAdd(&cursor[d], 1);
        colidx[pos] = src[e];
    }
}

// ---------- gather-aggregate: one wave/node, lane = 2 packed cols ----------
__global__ __launch_bounds__(256) void agg_kernel(
    const float* __restrict__ x, const unsigned short* __restrict__ xs,
    const float* __restrict__ dinv, const int* __restrict__ offs,
    const int* __restrict__ colidx, float* __restrict__ outp,
    unsigned int* __restrict__ aggb, int N) {
    int wid = (blockIdx.x * blockDim.x + threadIdx.x) >> 6;
    if (wid >= N) return;
    int lane = threadIdx.x & 63;
    float dv = dinv[wid];
    float a0, a1;
    int p = offs[wid], pe = offs[wid + 1];
    if (xs) {
        const unsigned int* xs32 = (const unsigned int*)xs;
        unsigned int sv = xs32[(size_t)wid * 64 + lane];
        a0 = bf2f((unsigned short)sv);
        a1 = bf2f((unsigned short)(sv >> 16));
        for (; p + 16 <= pe; p += 16) {
            int u[16];
            unsigned int v[16];
#pragma unroll
            for (int j = 0; j < 16; ++j) u[j] = colidx[p + j];
#pragma unroll
            for (int j = 0; j < 16; ++j) v[j] = xs32[(size_t)u[j] * 64 + lane];
#pragma unroll
            for (int j = 0; j < 16; ++j) {
                a0 += bf2f((unsigned short)v[j]);
                a1 += bf2f((unsigned short)(v[j] >> 16));
            }
        }
        for (; p + 4 <= pe; p += 4) {
            int u[4];
            unsigned int v[4];
#pragma unroll
            for (int j = 0; j < 4; ++j) u[j] = colidx[p + j];
#pragma unroll
            for (int j = 0; j < 4; ++j) v[j] = xs32[(size_t)u[j] * 64 + lane];
#pragma unroll
            for (int j = 0; j < 4; ++j) {
                a0 += bf2f((unsigned short)v[j]);
                a1 += bf2f((unsigned short)(v[j] >> 16));
            }
        }
        for (; p < pe; ++p) {
            unsigned int v = xs32[(size_t)colidx[p] * 64 + lane];
            a0 += bf2f((unsigned short)v);
            a1 += bf2f((unsigned short)(v >> 16));
        }
        aggb[(size_t)wid * 64 + lane] =
            (unsigned int)f2bf(dv * a0) | ((unsigned int)f2bf(dv * a1) << 16);
    } else {
        const float2* x2 = (const float2*)x;
        float2 s = x2[(size_t)wid * 64 + lane];
        a0 = dv * s.x;
        a1 = dv * s.y;
        for (; p < pe; ++p) {
            int u = colidx[p];
            float du = dinv[u];
            float2 vv = x2[(size_t)u * 64 + lane];
            a0 += du * vv.x;
            a1 += du * vv.y;
        }
        float2 r;
        r.x = dv * a0;
        r.y = dv * a1;
        ((float2*)outp)[(size_t)wid * 64 + lane] = r;
    }
}

// ---------- MFMA GEMM: out = relu(BN(agg @ W + b)) + x ----------
__global__ __launch_bounds__(256) void gemm_kernel(
    float* __restrict__ outp, const float* __restrict__ xg,
    const unsigned short* __restrict__ Wt, const unsigned short* __restrict__ aggb,
    const float* __restrict__ scv, const float* __restrict__ pov, int nTiles) {
    int wid = (blockIdx.x * blockDim.x + threadIdx.x) >> 6;
    if (wid >= nTiles) return;
    int lane = threadIdx.x & 63;
    int m = lane & 15, quad = lane >> 4;
    int row0 = wid * 16;

    short8 B[8][4];
#pragma unroll
    for (int cg = 0; cg < 8; ++cg)
#pragma unroll
        for (int ks = 0; ks < 4; ++ks)
            B[cg][ks] = *(const short8*)&Wt[(size_t)(cg * 16 + m) * D + ks * 32 + quad * 8];

    short8 A[4];
    if (aggb) {
        const unsigned short* arow = aggb + (size_t)(row0 + m) * D;
#pragma unroll
        for (int ks = 0; ks < 4; ++ks)
            A[ks] = *(const short8*)&arow[ks * 32 + quad * 8];
    } else {
        const float* arow = outp + (size_t)(row0 + m) * D;
#pragma unroll
        for (int ks = 0; ks < 4; ++ks) {
            float4 f0 = *(const float4*)(arow + ks * 32 + quad * 8);
            float4 f1 = *(const float4*)(arow + ks * 32 + quad * 8 + 4);
            short8 af;
            af[0] = (short)f2bf(f0.x); af[1] = (short)f2bf(f0.y);
            af[2] = (short)f2bf(f0.z); af[3] = (short)f2bf(f0.w);
            af[4] = (short)f2bf(f1.x); af[5] = (short)f2bf(f1.y);
            af[6] = (short)f2bf(f1.z); af[7] = (short)f2bf(f1.w);
            A[ks] = af;
        }
    }

#pragma unroll
    for (int cg = 0; cg < 8; ++cg) {
        floatx4 acc = {0.f, 0.f, 0.f, 0.f};
#pragma unroll
        for (int ks = 0; ks < 4; ++ks)
            acc = __builtin_amdgcn_mfma_f32_16x16x32_bf16(A[ks], B[cg][ks], acc, 0, 0, 0);
        int col = cg * 16 + m;
        float sc = scv[col], po = pov[col];
#pragma unroll
        for (int i = 0; i < 4; ++i) {
            int row = row0 + quad * 4 + i;
            float bn = acc[i] * sc + po;
            size_t idx = (size_t)row * D + col;
            outp[idx] = fmaxf(bn, 0.f) + xg[idx];
        }
    }
}

extern "C" void kernel_launch(void* const* d_in, const int* in_sizes, int n_in,
                              void* d_out, int out_size, void* d_ws, size_t ws_size,
                              hipStream_t stream) {
    const float* x = (const float*)d_in[0];
    const int* edge = (const int*)d_in[1];
    const float* Wm = (const float*)d_in[2];
    const float* b = (const float*)d_in[3];
    const float* gamma = (const float*)d_in[4];
    const float* beta = (const float*)d_in[5];
    const float* mean = (const float*)d_in[6];
    const float* var = (const float*)d_in[7];
    float* out = (float*)d_out;

    int N = in_sizes[0] / D;
    int E = in_sizes[1] / 2;
    const int* src = edge;
    const int* dst = edge + E;
    int P = (N + 255) / 256;

    // ---- workspace layout ----
    char* w = (char*)d_ws;
    size_t cur = 0;
    auto take = [&](size_t bytes) -> void* {
        cur = (cur + 15) & ~(size_t)15;
        void* p = w + cur;
        cur += bytes;
        return p;
    };
    int* deg = (int*)take((size_t)N * 4);
    int* bucketTot = (int*)take(NBUCK * 4);
    int* resCnt = (int*)take(NBUCK * 4);
    float* dinv = (float*)take((size_t)N * 4);
    int* offs = (int*)take((size_t)(N + 1) * 4);
    int* cursor = (int*)take((size_t)N * 4);
    int* bsum = (int*)take((size_t)(P + 1) * 4);
    unsigned short* Wt = (unsigned short*)take((size_t)D * D * 2);
    float* scv = (float*)take(D * 4);
    float* pov = (float*)take(D * 4);
    int* colidx = (int*)take((size_t)E * 4);
    cur = (cur + 15) & ~(size_t)15;
    size_t fixedEnd = cur;

    size_t xsBytes = (size_t)N * D * 2;
    size_t zoneBytes = (xsBytes > (size_t)E * 8) ? xsBytes : (size_t)E * 8;
    bool fast = fixedEnd + xsBytes + zoneBytes <= ws_size;

    unsigned short* xs = nullptr;
    int2* pairs = nullptr;
    unsigned int* aggb = nullptr;
    if (fast) {
        xs = (unsigned short*)(w + fixedEnd);
        pairs = (int2*)(w + fixedEnd + xsBytes);        // dead after sort_kernel
        aggb = (unsigned int*)(w + fixedEnd + xsBytes); // aliases pairs
    }

    wt_kernel<<<(D * D) / 256, 256, 0, stream>>>(Wm, b, gamma, beta, mean, var, Wt, scv,
                                                 pov, bucketTot, resCnt);

    if (fast) {
        pA_kernel<<<1024, 512, 0, stream>>>(dst, bucketTot, E);
        pB_kernel<<<1024, 512, 0, stream>>>(src, dst, bucketTot, resCnt, pairs, E);
        sort_kernel<<<NBUCK, 512, 0, stream>>>(pairs, bucketTot, deg, offs, colidx, N, E);
        xs_kernel<<<(N * 32 + 255) / 256, 256, 0, stream>>>(x, deg, dinv, xs, N * 32);
    } else {
        hipMemsetAsync(deg, 0, sizeof(int) * N, stream);
        deg_kernel<<<(E + 255) / 256, 256, 0, stream>>>(dst, deg, E);
        dinv_kernel<<<(N + 255) / 256, 256, 0, stream>>>(deg, dinv, N);
        scan1_kernel<<<P, 256, 0, stream>>>(deg, bsum, N);
        scan2_kernel<<<1, 512, 0, stream>>>(bsum, offs, P, N);
        scan3_kernel<<<P, 256, 0, stream>>>(deg, bsum, offs, cursor, N);
        fill_kernel<<<(E + 255) / 256, 256, 0, stream>>>(src, dst, cursor, colidx, E);
    }
    agg_kernel<<<(N * 64 + 255) / 256, 256, 0, stream>>>(x, xs, dinv, offs, colidx, out, aggb, N);
    int nTiles = (N + 15) / 16;
    gemm_kernel<<<(nTiles * 64 + 255) / 256, 256, 0, stream>>>(
        out, x, Wt, (const unsigned short*)aggb, scv, pov, nTiles);
}

// Round 4
// 286.686 us; speedup vs baseline: 1.2778x; 1.0524x over previous
//
#include <hip/hip_runtime.h>

#define D 128
#define BN_EPS 1e-5f
#define NBUCK 512     // coarse buckets, dst>>8 (391 used at N=100K), 256 nodes/bucket
#define BSHIFT 8
#define BNODES 256    // nodes per bucket

using short8 = __attribute__((ext_vector_type(8))) short;
using floatx4 = __attribute__((ext_vector_type(4))) float;

__device__ inline unsigned short f2bf(float f) {
    unsigned u = __float_as_uint(f);
    u += 0x7fff + ((u >> 16) & 1);  // RNE
    return (unsigned short)(u >> 16);
}
__device__ inline float bf2f(unsigned short s) {
    return __uint_as_float(((unsigned)s) << 16);
}

// ---------- wt: fallback-path only (fast path fuses this into pAwt) ----------
__global__ void wt_kernel(const float* __restrict__ W, const float* __restrict__ b,
                          const float* __restrict__ gamma, const float* __restrict__ beta,
                          const float* __restrict__ mean, const float* __restrict__ var,
                          unsigned short* __restrict__ Wt, float* __restrict__ scv,
                          float* __restrict__ pov) {
    int t = blockIdx.x * blockDim.x + threadIdx.x;
    int k = t >> 7, n = t & 127;
    Wt[(size_t)n * D + k] = f2bf(W[t]);
    if (t < D) {
        float sc = gamma[t] * rsqrtf(var[t] + BN_EPS);
        scv[t] = sc;
        pov[t] = (b[t] - mean[t]) * sc + beta[t];
    }
}

// ---------- pAwt: bucket histogram + fused Wt transpose / BN affine ----------
// All 1024 blocks histogram dst; blocks 0..15 additionally transpose W (2
// elements/thread); block 0 computes scv/pov. bucketTot pre-zeroed by memset.
__global__ __launch_bounds__(512) void pAwt_kernel(
    const int* __restrict__ dst, int* __restrict__ bucketTot, int E,
    const float* __restrict__ W, const float* __restrict__ b,
    const float* __restrict__ gamma, const float* __restrict__ beta,
    const float* __restrict__ mean, const float* __restrict__ var,
    unsigned short* __restrict__ Wt, float* __restrict__ scv,
    float* __restrict__ pov) {
    __shared__ int lh[NBUCK];
    int tid = threadIdx.x;
    lh[tid] = 0;
    __syncthreads();
    for (int i = blockIdx.x * 512 + tid; i < E; i += gridDim.x * 512)
        atomicAdd(&lh[dst[i] >> BSHIFT], 1);
    if (blockIdx.x < 16) {
        int t = blockIdx.x * 512 + tid;  // 0..8191
#pragma unroll
        for (int h = 0; h < 2; ++h) {
            int tt = t + h * 8192;
            Wt[(size_t)(tt & 127) * D + (tt >> 7)] = f2bf(W[tt]);
        }
        if (blockIdx.x == 0 && tid < D) {
            float sc = gamma[tid] * rsqrtf(var[tid] + BN_EPS);
            scv[tid] = sc;
            pov[tid] = (b[tid] - mean[tid]) * sc + beta[tid];
        }
    }
    __syncthreads();
    if (lh[tid]) atomicAdd(&bucketTot[tid], lh[tid]);
}

// ---------- pB: partition into bucket order (self-scanned bases) ----------
__global__ __launch_bounds__(512) void pB_kernel(const int* __restrict__ src,
                                                 const int* __restrict__ dst,
                                                 const int* __restrict__ bucketTot,
                                                 int* __restrict__ resCnt,
                                                 int2* __restrict__ pairs, int E) {
    __shared__ int sb[NBUCK];
    __shared__ int lh[NBUCK];
    __shared__ int lcur[NBUCK];
    int tid = threadIdx.x;
    sb[tid] = bucketTot[tid];
    lh[tid] = 0;
    __syncthreads();
    for (int d = 1; d < NBUCK; d <<= 1) {
        int v = (tid >= d) ? sb[tid - d] : 0;
        __syncthreads();
        sb[tid] += v;
        __syncthreads();
    }
    // sb = inclusive scan; exclusive base for bucket t = sb[t] - bucketTot[t]
    int chunk = (E + gridDim.x - 1) / gridDim.x;
    int base = blockIdx.x * chunk;
    int lim = min(chunk, E - base);
    if (lim <= 0) return;
    for (int i = tid; i < lim; i += 512) atomicAdd(&lh[dst[base + i] >> BSHIFT], 1);
    __syncthreads();
    int c = lh[tid];
    lcur[tid] = c ? (sb[tid] - bucketTot[tid]) + atomicAdd(&resCnt[tid], c) : 0;
    __syncthreads();
    for (int i = tid; i < lim; i += 512) {
        int s = src[base + i], d2 = dst[base + i];
        int pos = atomicAdd(&lcur[d2 >> BSHIFT], 1);
        pairs[pos] = make_int2(s, d2);
    }
}

// ---------- sortxs: within-bucket counting sort + fused xs/dinv build ----------
// One block per bucket (BNODES=256 nodes). deg is computed block-locally, so
// the xs conversion (x * dinv -> bf16) for this bucket's nodes fuses here.
__global__ __launch_bounds__(512) void sortxs_kernel(
    const int2* __restrict__ pairs, const int* __restrict__ bucketTot,
    const float* __restrict__ x, int* __restrict__ deg, int* __restrict__ offs,
    int* __restrict__ colidx, float* __restrict__ dinv,
    unsigned short* __restrict__ xs, int N, int E) {
    __shared__ int sb[NBUCK];
    __shared__ int lh[BNODES];
    __shared__ int lcur[BNODES];
    __shared__ float sdv[BNODES];
    int tid = threadIdx.x;
    int b = blockIdx.x;
    sb[tid] = bucketTot[tid];
    __syncthreads();
    for (int d = 1; d < NBUCK; d <<= 1) {
        int v = (tid >= d) ? sb[tid - d] : 0;
        __syncthreads();
        sb[tid] += v;
        __syncthreads();
    }
    int cnt = bucketTot[b];
    int base = sb[b] - cnt;  // exclusive bucket base
    if (tid < BNODES) lh[tid] = 0;
    __syncthreads();
    for (int i = tid; i < cnt; i += 512)
        atomicAdd(&lh[pairs[base + i].y & (BNODES - 1)], 1);
    __syncthreads();
    int orig = (tid < BNODES) ? lh[tid] : 0;
    for (int d = 1; d < BNODES; d <<= 1) {
        int v = (tid < BNODES && tid >= d) ? lh[tid - d] : 0;
        __syncthreads();
        if (tid < BNODES) lh[tid] += v;
        __syncthreads();
    }
    if (tid < BNODES) {
        int exc = lh[tid] - orig;
        int node = b * BNODES + tid;
        float dvv = rsqrtf((float)(orig + 1));
        sdv[tid] = dvv;
        if (node < N) {
            deg[node] = orig;
            offs[node] = base + exc;
            dinv[node] = dvv;
        }
        lcur[tid] = exc;
    }
    if (b == 0 && tid == 0) offs[N] = E;
    __syncthreads();
    // scatter colidx (grouped by dst within this bucket's window)
    for (int i = tid; i < cnt; i += 512) {
        int2 p = pairs[base + i];
        int pos = atomicAdd(&lcur[p.y & (BNODES - 1)], 1);
        colidx[base + pos] = p.x;
    }
    // xs build for this bucket's nodes (sdv valid since the barrier above)
    int nb = min(BNODES, N - b * BNODES);
    if (nb > 0) {
        const float4* x4 = (const float4*)x;
        ushort4* xs4 = (ushort4*)xs;
        int tot = nb * 32;  // 32 float4 chunks per node
        for (int c = tid; c < tot; c += 512) {
            int nl = c >> 5, q = c & 31;
            int node = b * BNODES + nl;
            float dvv = sdv[nl];
            float4 f = x4[(size_t)node * 32 + q];
            ushort4 o;
            o.x = f2bf(dvv * f.x); o.y = f2bf(dvv * f.y);
            o.z = f2bf(dvv * f.z); o.w = f2bf(dvv * f.w);
            xs4[(size_t)node * 32 + q] = o;
        }
    }
}

// ---------- fallback kernels (small-ws path) ----------
__global__ void deg_kernel(const int* __restrict__ dst, int* __restrict__ deg, int E) {
    int e = blockIdx.x * blockDim.x + threadIdx.x;
    if (e < E) atomicAdd(&deg[dst[e]], 1);
}

__global__ void dinv_kernel(const int* __restrict__ deg, float* __restrict__ dinv, int N) {
    int v = blockIdx.x * blockDim.x + threadIdx.x;
    if (v < N) dinv[v] = rsqrtf((float)(deg[v] + 1));
}

__global__ __launch_bounds__(256) void scan1_kernel(const int* __restrict__ deg,
                                                    int* __restrict__ bsum, int N) {
    __shared__ int s[256];
    int t = threadIdx.x;
    int v = blockIdx.x * 256 + t;
    s[t] = (v < N) ? deg[v] : 0;
    for (int st = 128; st > 0; st >>= 1) {
        __syncthreads();
        if (t < st) s[t] += s[t + st];
    }
    if (t == 0) bsum[blockIdx.x] = s[0];
}

__global__ __launch_bounds__(512) void scan2_kernel(int* __restrict__ bsum,
                                                    int* __restrict__ offs, int P, int N) {
    __shared__ int a[512];
    int t = threadIdx.x;
    int orig = (t < P) ? bsum[t] : 0;
    a[t] = orig;
    __syncthreads();
    for (int d = 1; d < 512; d <<= 1) {
        int tv = (t >= d) ? a[t - d] : 0;
        __syncthreads();
        a[t] += tv;
        __syncthreads();
    }
    if (t < P) bsum[t] = a[t] - orig;
    if (t == 0) offs[N] = a[511];
}

__global__ __launch_bounds__(256) void scan3_kernel(const int* __restrict__ deg,
                                                    const int* __restrict__ bsum,
                                                    int* __restrict__ offs,
                                                    int* __restrict__ cursor, int N) {
    __shared__ int a[256];
    int t = threadIdx.x;
    int v = blockIdx.x * 256 + t;
    int d = (v < N) ? deg[v] : 0;
    a[t] = d;
    __syncthreads();
    for (int st = 1; st < 256; st <<= 1) {
        int tv = (t >= st) ? a[t - st] : 0;
        __syncthreads();
        a[t] += tv;
        __syncthreads();
    }
    if (v < N) {
        int off = bsum[blockIdx.x] + a[t] - d;
        offs[v] = off;
        cursor[v] = off;
    }
}

__global__ void fill_kernel(const int* __restrict__ src, const int* __restrict__ dst,
                            int* __restrict__ cursor, int* __restrict__ colidx, int E) {
    int e = blockIdx.x * blockDim.x + threadIdx.x;
    if (e < E) {
        int d = dst[e];
        int pos = atomicAdd(&cursor[d], 1);
        colidx[pos] = src[e];
    }
}

// ---------- gather-aggregate: one wave/node, lane = 2 packed cols ----------
__global__ __launch_bounds__(256) void agg_kernel(
    const float* __restrict__ x, const unsigned short* __restrict__ xs,
    const float* __restrict__ dinv, const int* __restrict__ offs,
    const int* __restrict__ colidx, float* __restrict__ outp,
    unsigned int* __restrict__ aggb, int N) {
    int wid = (blockIdx.x * blockDim.x + threadIdx.x) >> 6;
    if (wid >= N) return;
    int lane = threadIdx.x & 63;
    float dv = dinv[wid];
    float a0, a1;
    int p = offs[wid], pe = offs[wid + 1];
    if (xs) {
        const unsigned int* xs32 = (const unsigned int*)xs;
        unsigned int sv = xs32[(size_t)wid * 64 + lane];
        a0 = bf2f((unsigned short)sv);
        a1 = bf2f((unsigned short)(sv >> 16));
        for (; p + 16 <= pe; p += 16) {
            int u[16];
            unsigned int v[16];
#pragma unroll
            for (int j = 0; j < 16; ++j) u[j] = colidx[p + j];
#pragma unroll
            for (int j = 0; j < 16; ++j) v[j] = xs32[(size_t)u[j] * 64 + lane];
#pragma unroll
            for (int j = 0; j < 16; ++j) {
                a0 += bf2f((unsigned short)v[j]);
                a1 += bf2f((unsigned short)(v[j] >> 16));
            }
        }
        for (; p + 4 <= pe; p += 4) {
            int u[4];
            unsigned int v[4];
#pragma unroll
            for (int j = 0; j < 4; ++j) u[j] = colidx[p + j];
#pragma unroll
            for (int j = 0; j < 4; ++j) v[j] = xs32[(size_t)u[j] * 64 + lane];
#pragma unroll
            for (int j = 0; j < 4; ++j) {
                a0 += bf2f((unsigned short)v[j]);
                a1 += bf2f((unsigned short)(v[j] >> 16));
            }
        }
        for (; p < pe; ++p) {
            unsigned int v = xs32[(size_t)colidx[p] * 64 + lane];
            a0 += bf2f((unsigned short)v);
            a1 += bf2f((unsigned short)(v >> 16));
        }
        aggb[(size_t)wid * 64 + lane] =
            (unsigned int)f2bf(dv * a0) | ((unsigned int)f2bf(dv * a1) << 16);
    } else {
        const float2* x2 = (const float2*)x;
        float2 s = x2[(size_t)wid * 64 + lane];
        a0 = dv * s.x;
        a1 = dv * s.y;
        for (; p < pe; ++p) {
            int u = colidx[p];
            float du = dinv[u];
            float2 vv = x2[(size_t)u * 64 + lane];
            a0 += du * vv.x;
            a1 += du * vv.y;
        }
        float2 r;
        r.x = dv * a0;
        r.y = dv * a1;
        ((float2*)outp)[(size_t)wid * 64 + lane] = r;
    }
}

// ---------- MFMA GEMM: out = relu(BN(agg @ W + b)) + x ----------
// Wt staged once per block in LDS (32KB), XOR-swizzled so B-fragment
// ds_read_b128 is conflict-free. Cuts per-wave 128-VGPR B arrays (~200->~60
// VGPR) and 800MB of L2 Wt re-reads (32KB/wave x 25K waves) to 50MB.
__global__ __launch_bounds__(256) void gemm_kernel(
    float* __restrict__ outp, const float* __restrict__ xg,
    const unsigned short* __restrict__ Wt, const unsigned short* __restrict__ aggb,
    const float* __restrict__ scv, const float* __restrict__ pov, int nTiles) {
    __shared__ uint4 sW4[2048];  // 32KB: [row 0..127][c4 0..15] swizzled c4^=(row&7)
    int tid = threadIdx.x;
    const uint4* W4 = (const uint4*)Wt;
#pragma unroll
    for (int i = 0; i < 8; ++i) {
        int q = tid + i * 256;  // uint4 index 0..2047
        int row = q >> 4, c4 = q & 15;
        sW4[row * 16 + (c4 ^ (row & 7))] = W4[q];
    }
    __syncthreads();

    int wid = (blockIdx.x * blockDim.x + tid) >> 6;
    if (wid >= nTiles) return;
    int lane = tid & 63;
    int m = lane & 15, quad = lane >> 4;
    int row0 = wid * 16;

    short8 A[4];
    if (aggb) {
        const unsigned short* arow = aggb + (size_t)(row0 + m) * D;
#pragma unroll
        for (int ks = 0; ks < 4; ++ks)
            A[ks] = *(const short8*)&arow[ks * 32 + quad * 8];
    } else {
        const float* arow = outp + (size_t)(row0 + m) * D;
#pragma unroll
        for (int ks = 0; ks < 4; ++ks) {
            float4 f0 = *(const float4*)(arow + ks * 32 + quad * 8);
            float4 f1 = *(const float4*)(arow + ks * 32 + quad * 8 + 4);
            short8 af;
            af[0] = (short)f2bf(f0.x); af[1] = (short)f2bf(f0.y);
            af[2] = (short)f2bf(f0.z); af[3] = (short)f2bf(f0.w);
            af[4] = (short)f2bf(f1.x); af[5] = (short)f2bf(f1.y);
            af[6] = (short)f2bf(f1.z); af[7] = (short)f2bf(f1.w);
            A[ks] = af;
        }
    }

#pragma unroll
    for (int cg = 0; cg < 8; ++cg) {
        int brow = cg * 16 + m;
        floatx4 acc = {0.f, 0.f, 0.f, 0.f};
#pragma unroll
        for (int ks = 0; ks < 4; ++ks) {
            short8 Bf = *(const short8*)&sW4[brow * 16 + ((ks * 4 + quad) ^ (m & 7))];
            acc = __builtin_amdgcn_mfma_f32_16x16x32_bf16(A[ks], Bf, acc, 0, 0, 0);
        }
        int col = cg * 16 + m;
        float sc = scv[col], po = pov[col];
#pragma unroll
        for (int i = 0; i < 4; ++i) {
            int row = row0 + quad * 4 + i;
            float bn = acc[i] * sc + po;
            size_t idx = (size_t)row * D + col;
            outp[idx] = fmaxf(bn, 0.f) + xg[idx];
        }
    }
}

extern "C" void kernel_launch(void* const* d_in, const int* in_sizes, int n_in,
                              void* d_out, int out_size, void* d_ws, size_t ws_size,
                              hipStream_t stream) {
    const float* x = (const float*)d_in[0];
    const int* edge = (const int*)d_in[1];
    const float* Wm = (const float*)d_in[2];
    const float* b = (const float*)d_in[3];
    const float* gamma = (const float*)d_in[4];
    const float* beta = (const float*)d_in[5];
    const float* mean = (const float*)d_in[6];
    const float* var = (const float*)d_in[7];
    float* out = (float*)d_out;

    int N = in_sizes[0] / D;
    int E = in_sizes[1] / 2;
    const int* src = edge;
    const int* dst = edge + E;
    int P = (N + 255) / 256;

    // ---- workspace layout ----
    char* w = (char*)d_ws;
    size_t cur = 0;
    auto take = [&](size_t bytes) -> void* {
        cur = (cur + 15) & ~(size_t)15;
        void* p = w + cur;
        cur += bytes;
        return p;
    };
    int* deg = (int*)take((size_t)N * 4);
    int* bucketTot = (int*)take(NBUCK * 4);
    int* resCnt = (int*)take(NBUCK * 4);  // contiguous with bucketTot (one memset)
    float* dinv = (float*)take((size_t)N * 4);
    int* offs = (int*)take((size_t)(N + 1) * 4);
    int* cursor = (int*)take((size_t)N * 4);
    int* bsum = (int*)take((size_t)(P + 1) * 4);
    unsigned short* Wt = (unsigned short*)take((size_t)D * D * 2);
    float* scv = (float*)take(D * 4);
    float* pov = (float*)take(D * 4);
    int* colidx = (int*)take((size_t)E * 4);
    cur = (cur + 15) & ~(size_t)15;
    size_t fixedEnd = cur;

    size_t xsBytes = (size_t)N * D * 2;
    size_t zoneBytes = (xsBytes > (size_t)E * 8) ? xsBytes : (size_t)E * 8;
    bool fast = fixedEnd + xsBytes + zoneBytes <= ws_size;

    unsigned short* xs = nullptr;
    int2* pairs = nullptr;
    unsigned int* aggb = nullptr;
    if (fast) {
        xs = (unsigned short*)(w + fixedEnd);
        pairs = (int2*)(w + fixedEnd + xsBytes);        // dead after sortxs_kernel
        aggb = (unsigned int*)(w + fixedEnd + xsBytes); // aliases pairs
    }

    if (fast) {
        hipMemsetAsync(bucketTot, 0, (size_t)NBUCK * 8, stream);  // bucketTot+resCnt
        pAwt_kernel<<<1024, 512, 0, stream>>>(dst, bucketTot, E, Wm, b, gamma, beta,
                                              mean, var, Wt, scv, pov);
        pB_kernel<<<1024, 512, 0, stream>>>(src, dst, bucketTot, resCnt, pairs, E);
        sortxs_kernel<<<NBUCK, 512, 0, stream>>>(pairs, bucketTot, x, deg, offs, colidx,
                                                 dinv, xs, N, E);
    } else {
        wt_kernel<<<(D * D) / 256, 256, 0, stream>>>(Wm, b, gamma, beta, mean, var, Wt,
                                                     scv, pov);
        hipMemsetAsync(deg, 0, sizeof(int) * N, stream);
        deg_kernel<<<(E + 255) / 256, 256, 0, stream>>>(dst, deg, E);
        dinv_kernel<<<(N + 255) / 256, 256, 0, stream>>>(deg, dinv, N);
        scan1_kernel<<<P, 256, 0, stream>>>(deg, bsum, N);
        scan2_kernel<<<1, 512, 0, stream>>>(bsum, offs, P, N);
        scan3_kernel<<<P, 256, 0, stream>>>(deg, bsum, offs, cursor, N);
        fill_kernel<<<(E + 255) / 256, 256, 0, stream>>>(src, dst, cursor, colidx, E);
    }
    agg_kernel<<<(N * 64 + 255) / 256, 256, 0, stream>>>(x, xs, dinv, offs, colidx, out,
                                                         aggb, N);
    int nTiles = (N + 15) / 16;
    gemm_kernel<<<(nTiles * 64 + 255) / 256, 256, 0, stream>>>(
        out, x, Wt, (const unsigned short*)aggb, scv, pov, nTiles);
}